// Round 16
// baseline (119.783 us; speedup 1.0000x reference)
//
#include <hip/hip_runtime.h>
#include <math.h>

#define NHALF 4096
#define NTOT  8192
#define DIN   512
#define DFR   50     // real deep-feature dim
#define FPS   160    // packed feature row length (shorts): [50|50|50|10 pad]
#define BM    128    // tile M = N
#define NBI   64     // 8192/128
#define NTRI  2080   // 64*65/2 upper-tri blocks
// Xb8 layout: [t64 0..7][kc 0..7][row 0..8191][8B]; strides 524288 / 65536 / 8
#define T64STRIDE 524288
#define KCSTRIDE  65536
#define FIXSCALE  16777216.0   // 2^24 fixed-point scale for the block-sum atomics

typedef short short8 __attribute__((ext_vector_type(8)));
typedef float f32x4 __attribute__((ext_vector_type(4)));
typedef int   i32x8 __attribute__((ext_vector_type(8)));

__device__ __forceinline__ float softplus_f(float x) {
    return fmaxf(x, 0.f) + log1pf(expf(-fabsf(x)));
}

__device__ __forceinline__ unsigned cvt_pk_bf16(float lo, float hi) {
    unsigned r;
    asm("v_cvt_pk_bf16_f32 %0, %1, %2" : "=v"(r) : "v"(lo), "v"(hi));
    return r;
}

__device__ __forceinline__ unsigned short bf16_rne(float v) {
    return (unsigned short)(cvt_pk_bf16(v, 0.f) & 0xffffu);
}

__device__ __forceinline__ float bf16_to_f(unsigned short s) {
    union { unsigned u; float f; } c;
    c.u = (unsigned)s << 16;
    return c.f;
}

__device__ __forceinline__ void gload_lds16(const void* g, void* l) {
    __builtin_amdgcn_global_load_lds(
        (const __attribute__((address_space(1))) void*)g,
        (__attribute__((address_space(3))) void*)l, 16, 0, 0);
}

// ---------------- Kernel A: featurize (lane-parallel MLP, 2 rows/wave) ----------------
// X: q = e4m3(64*x/sigmaOPT) stored transposed [t64][kc][row]; norms from
// DEQUANTIZED q. F: f = 64*o/sigma0OPT as bf16 hi+lo packs. Layers 2-4:
// lane j owns neuron j (1 softplus each), broadcast via shfl. ep-terms dropped.
// 1024 blocks x 8 rows: W1 LDS staging amortized 2x vs round 15.
__global__ __launch_bounds__(256) void featurize_kernel(
    const float* __restrict__ Xs, const float* __restrict__ Xt,
    const float* __restrict__ W1, const float* __restrict__ b1,
    const float* __restrict__ W2, const float* __restrict__ b2,
    const float* __restrict__ W3, const float* __restrict__ b3,
    const float* __restrict__ W4, const float* __restrict__ b4,
    const float* __restrict__ sigP, const float* __restrict__ sig0P,
    unsigned short* __restrict__ FpkA, unsigned short* __restrict__ FpkB,
    float* __restrict__ normC, char* __restrict__ Xb8)
{
    __shared__ float W1L[80 * 65];                       // 20.8 KB
    __shared__ __align__(16) unsigned short pkA[4][FPS]; // per-wave private
    __shared__ __align__(16) unsigned short pkB[4][FPS];
    int tid = threadIdx.x;
    for (int e = tid; e < 5120; e += 256) {
        int r = e / 10, j = e - 10 * r;
        W1L[((r & 7) * 10 + j) * 65 + (r >> 3)] = W1[e];
    }
    __syncthreads();

    int lane = tid & 63, wv = tid >> 6;
    int lane10 = lane % 10;
    float alpha8 = 64.f / sigP[0];    // 64/sigmaOPT
    float beta   = 64.f / sig0P[0];   // 64/sigma0OPT

    for (int it = 0; it < 2; ++it) {
        int row = blockIdx.x * 8 + wv * 2 + it;
        const float* src = (row < NHALF) ? (Xs + (size_t)row * DIN)
                                         : (Xt + (size_t)(row - NHALF) * DIN);
        float4 v0 = ((const float4*)src)[lane * 2];
        float4 v1 = ((const float4*)src)[lane * 2 + 1];
        float x[8] = {v0.x, v0.y, v0.z, v0.w, v1.x, v1.y, v1.z, v1.w};

        // fp8 quantize (x64 scale), dequantized norm
        float z[8];
#pragma unroll
        for (int t = 0; t < 8; ++t) z[t] = x[t] * alpha8;
        unsigned w0 = 0, w1 = 0;
        w0 = __builtin_amdgcn_cvt_pk_fp8_f32(z[0], z[1], w0, false);
        w0 = __builtin_amdgcn_cvt_pk_fp8_f32(z[2], z[3], w0, true);
        w1 = __builtin_amdgcn_cvt_pk_fp8_f32(z[4], z[5], w1, false);
        w1 = __builtin_amdgcn_cvt_pk_fp8_f32(z[6], z[7], w1, true);
        float on = 0.f, qf;
        qf = __builtin_amdgcn_cvt_f32_fp8(w0, 0); on = fmaf(qf, qf, on);
        qf = __builtin_amdgcn_cvt_f32_fp8(w0, 1); on = fmaf(qf, qf, on);
        qf = __builtin_amdgcn_cvt_f32_fp8(w0, 2); on = fmaf(qf, qf, on);
        qf = __builtin_amdgcn_cvt_f32_fp8(w0, 3); on = fmaf(qf, qf, on);
        qf = __builtin_amdgcn_cvt_f32_fp8(w1, 0); on = fmaf(qf, qf, on);
        qf = __builtin_amdgcn_cvt_f32_fp8(w1, 1); on = fmaf(qf, qf, on);
        qf = __builtin_amdgcn_cvt_f32_fp8(w1, 2); on = fmaf(qf, qf, on);
        qf = __builtin_amdgcn_cvt_f32_fp8(w1, 3); on = fmaf(qf, qf, on);
        *(uint2*)(Xb8 + (lane >> 3) * T64STRIDE + (lane & 7) * KCSTRIDE
                  + (size_t)row * 8) = make_uint2(w0, w1);

        float p[10];
#pragma unroll
        for (int j = 0; j < 10; ++j) p[j] = 0.f;
#pragma unroll
        for (int t = 0; t < 8; ++t) {
            float xv = x[t];
#pragma unroll
            for (int j = 0; j < 10; ++j)
                p[j] = fmaf(xv, W1L[(t * 10 + j) * 65 + lane], p[j]);
        }
#pragma unroll
        for (int m = 32; m >= 1; m >>= 1) {
#pragma unroll
            for (int j = 0; j < 10; ++j) p[j] += __shfl_xor(p[j], m, 64);
            on += __shfl_xor(on, m, 64);
        }
        // layers 2-4: lane-parallel neurons (lane j owns neuron j%10)
        float pown = p[0];
#pragma unroll
        for (int j = 1; j < 10; ++j) pown = (lane10 == j) ? p[j] : pown;
        float hown = softplus_f(pown + b1[lane10]);
        float h1b[10];
#pragma unroll
        for (int k = 0; k < 10; ++k) h1b[k] = __shfl(hown, k, 64);

        float a2 = b2[lane10];
#pragma unroll
        for (int k = 0; k < 10; ++k) a2 = fmaf(h1b[k], W2[k * 10 + lane10], a2);
        float h2own = softplus_f(a2);
        float h2b[10];
#pragma unroll
        for (int k = 0; k < 10; ++k) h2b[k] = __shfl(h2own, k, 64);

        float a3 = b3[lane10];
#pragma unroll
        for (int k = 0; k < 10; ++k) a3 = fmaf(h2b[k], W3[k * 10 + lane10], a3);
        float h3own = softplus_f(a3);
        float h3b[10];
#pragma unroll
        for (int k = 0; k < 10; ++k) h3b[k] = __shfl(h3own, k, 64);

        float o = 0.f;
        if (lane < DFR) {
            float a = b4[lane];
#pragma unroll
            for (int k = 0; k < 10; ++k) a = fmaf(h3b[k], W4[k * 50 + lane], a);
            o = a;
        }
        // scaled split-pack: f = beta*o = hi + lo (both bf16)
        float f = o * beta;
        unsigned short hi_s = bf16_rne(f);
        unsigned short lo_s = bf16_rne(f - bf16_to_f(hi_s));
        if (lane < DFR) {
            pkA[wv][lane] = hi_s;  pkA[wv][50 + lane] = hi_s;  pkA[wv][100 + lane] = lo_s;
            pkB[wv][lane] = hi_s;  pkB[wv][50 + lane] = lo_s;  pkB[wv][100 + lane] = hi_s;
        } else if (lane < 60) {
            pkA[wv][100 + lane] = 0;   // pad 150..159
            pkB[wv][100 + lane] = 0;
        }
        // pkA/pkB slices are wave-private; intra-wave LDS RAW is HW/compiler ordered
        if (lane < 20)
            *(uint4*)(FpkA + (size_t)row * FPS + lane * 8) = *(const uint4*)&pkA[wv][lane * 8];
        else if (lane < 40)
            *(uint4*)(FpkB + (size_t)row * FPS + (lane - 20) * 8) = *(const uint4*)&pkB[wv][(lane - 20) * 8];

        float fn = f * f;
#pragma unroll
        for (int m = 32; m >= 1; m >>= 1) fn += __shfl_xor(fn, m, 64);
        if (lane == 0) normC[row] = (on + fn) * (1.f / 4096.f);
    }
}

// ---------------- Kernel C: MX-scaled fp8(X) + bf16(F) MFMA pairwise, upper-tri ----------------
// (round-15 proven compute) 4 x K=128 mfma_scale_f32_16x16x128_f8f6f4 (scale=1.0)
// + 5 x K=32 bf16; 3 x 16KB slots, counted vmcnt; BARR1/BARR2 race-free barriers.
// NEW: block partial sums go to a fixed-point int64 global accumulator (exact,
// order-independent -> bit-deterministic); the last block finalizes out[0].
__global__ __launch_bounds__(256, 3) void pairwise_kernel(
    const char* __restrict__ Xb8,
    const unsigned short* __restrict__ FpkA,
    const unsigned short* __restrict__ FpkB,
    const float* __restrict__ normC,
    unsigned long long* __restrict__ accI,
    unsigned int* __restrict__ doneCnt,
    float* __restrict__ out)
{
    __shared__ char smem[49152] __attribute__((aligned(128)));
    __shared__ double sredC[4];

    int bid = blockIdx.x;
    int bi = (int)((129.0 - sqrt(16641.0 - 8.0 * (double)bid)) * 0.5);
    while (NBI * (bi + 1) - (bi + 1) * bi / 2 <= bid) ++bi;
    while (NBI * bi - bi * (bi - 1) / 2 > bid) --bi;
    int bj = bi + (bid - (NBI * bi - bi * (bi - 1) / 2));

    int tid = threadIdx.x;
    int lane = tid & 63, wave = tid >> 6;
    int g = lane >> 4, l15 = lane & 15;
    int i0w = (wave >> 1) * 64;
    int j0w = (wave & 1) * 64;
    int ri = bi * BM, rj = bj * BM;

    const char* sA8 = Xb8 + wave * KCSTRIDE + (size_t)(ri + 2 * lane) * 8;
    const char* sB8 = Xb8 + wave * KCSTRIDE + (size_t)(rj + 2 * lane) * 8;
    int srow = tid >> 2;
    int schunk = (tid & 3) ^ ((srow >> 1) & 3);
    const char* fA0 = (const char*)(FpkA + (size_t)(ri + srow) * FPS) + schunk * 16;
    const char* fB0 = (const char*)(FpkB + (size_t)(rj + srow) * FPS) + schunk * 16;
    char* lwave = (char*)smem + wave * 1024;

    // F fragment read offsets (swizzled, shorts): row pitch 32, chunk 8
    int swz = (l15 >> 1) & 3;
    int offA = (i0w + l15) * 32 + (g ^ swz) * 8;
    int offB = (j0w + l15) * 32 + (g ^ swz) * 8;

    f32x4 acc[4][4];
#pragma unroll
    for (int a = 0; a < 4; ++a)
#pragma unroll
        for (int b = 0; b < 4; ++b) acc[a][b] = (f32x4){0.f, 0.f, 0.f, 0.f};

#define STAGE8(kt, buf)                                              \
    do {                                                             \
        char* ld_ = lwave + (buf) * 16384;                           \
        const char* a_ = sA8 + (kt) * T64STRIDE;                     \
        const char* b_ = sB8 + (kt) * T64STRIDE;                     \
        gload_lds16(a_,                ld_);                         \
        gload_lds16(a_ + 4 * KCSTRIDE, ld_ + 4096);                  \
        gload_lds16(b_,                ld_ + 8192);                  \
        gload_lds16(b_ + 4 * KCSTRIDE, ld_ + 12288);                 \
    } while (0)

#define STAGEF(kf, buf)                                              \
    do {                                                             \
        char* ld_ = lwave + (buf) * 16384;                           \
        const char* gA_ = fA0 + (kf) * 64;                           \
        const char* gB_ = fB0 + (kf) * 64;                           \
        gload_lds16(gA_,         ld_);                               \
        gload_lds16(gA_ + 20480, ld_ + 4096);                        \
        gload_lds16(gB_,         ld_ + 8192);                        \
        gload_lds16(gB_ + 20480, ld_ + 12288);                       \
    } while (0)

// K=128 MX-scaled phase consuming slot pair (pa = t64 even, pb = t64 odd).
#define C128(pa, pb)                                                               \
    do {                                                                           \
        const char* slA_ = smem + (((lane & 32) ? (pb) : (pa)) * 16384);           \
        int kcb_ = ((lane >> 4) & 1) << 2;                                         \
        const char* baseA_ = slA_ + kcb_ * 1024 + (i0w + l15) * 8;                 \
        const char* baseB_ = slA_ + 8192 + kcb_ * 1024 + (j0w + l15) * 8;          \
        i32x8 af_[4];                                                              \
        _Pragma("unroll")                                                          \
        for (int a = 0; a < 4; ++a) {                                              \
            const char* p_ = baseA_ + a * 128;                                     \
            uint2 t0 = *(const uint2*)(p_);                                        \
            uint2 t1 = *(const uint2*)(p_ + 1024);                                 \
            uint2 t2 = *(const uint2*)(p_ + 2048);                                 \
            uint2 t3 = *(const uint2*)(p_ + 3072);                                 \
            af_[a] = (i32x8){(int)t0.x, (int)t0.y, (int)t1.x, (int)t1.y,           \
                             (int)t2.x, (int)t2.y, (int)t3.x, (int)t3.y};          \
        }                                                                          \
        __builtin_amdgcn_s_setprio(1);                                             \
        _Pragma("unroll")                                                          \
        for (int b = 0; b < 4; ++b) {                                              \
            const char* p_ = baseB_ + b * 128;                                     \
            uint2 t0 = *(const uint2*)(p_);                                        \
            uint2 t1 = *(const uint2*)(p_ + 1024);                                 \
            uint2 t2 = *(const uint2*)(p_ + 2048);                                 \
            uint2 t3 = *(const uint2*)(p_ + 3072);                                 \
            i32x8 bf_ = (i32x8){(int)t0.x, (int)t0.y, (int)t1.x, (int)t1.y,        \
                                (int)t2.x, (int)t2.y, (int)t3.x, (int)t3.y};       \
            _Pragma("unroll")                                                      \
            for (int a = 0; a < 4; ++a)                                            \
                acc[a][b] = __builtin_amdgcn_mfma_scale_f32_16x16x128_f8f6f4(      \
                    af_[a], bf_, acc[a][b], 0, 0,                                  \
                    0, 0x7f7f7f7f, 0, 0x7f7f7f7f);                                 \
        }                                                                          \
        __builtin_amdgcn_s_setprio(0);                                             \
    } while (0)

#define C16(buf)                                                                   \
    do {                                                                           \
        const unsigned short* tc_ = (const unsigned short*)(smem + (buf) * 16384); \
        short8 af_[4], bf_[4];                                                     \
        _Pragma("unroll")                                                          \
        for (int a = 0; a < 4; ++a)                                                \
            af_[a] = *(const short8*)(tc_ + offA + a * 512);                       \
        _Pragma("unroll")                                                          \
        for (int b = 0; b < 4; ++b)                                                \
            bf_[b] = *(const short8*)(tc_ + 4096 + offB + b * 512);                \
        __builtin_amdgcn_s_setprio(1);                                             \
        _Pragma("unroll")                                                          \
        for (int a = 0; a < 4; ++a)                                                \
            _Pragma("unroll")                                                      \
            for (int b = 0; b < 4; ++b)                                            \
                acc[a][b] = __builtin_amdgcn_mfma_f32_16x16x32_bf16(               \
                    af_[a], bf_[b], acc[a][b], 0, 0, 0);                           \
        __builtin_amdgcn_s_setprio(0);                                             \
    } while (0)

#define WAITV(N) do { asm volatile("s_waitcnt vmcnt(" #N ")" ::: "memory");        \
                      __builtin_amdgcn_sched_barrier(0); } while (0)
#define BARR1    do { __builtin_amdgcn_s_barrier();                                \
                      __builtin_amdgcn_sched_barrier(0); } while (0)
#define BARR2    do { __builtin_amdgcn_sched_barrier(0);                           \
                      asm volatile("s_waitcnt lgkmcnt(0)" ::: "memory");           \
                      __builtin_amdgcn_sched_barrier(0);                           \
                      __builtin_amdgcn_s_barrier();                                \
                      __builtin_amdgcn_sched_barrier(0); } while (0)

    // ---- 9-phase pipelined loop: units u0..u7 (X t64) + f0..f4 (F) ----
    STAGE8(0, 0); STAGE8(1, 1); STAGE8(2, 2);
    WAITV(4); BARR1; C128(0, 1); BARR2; STAGE8(3, 0); STAGE8(4, 1);  // P0: u0,u1
    WAITV(4); BARR1; C128(2, 0); BARR2; STAGE8(5, 2); STAGE8(6, 0);  // P1: u2,u3
    WAITV(4); BARR1; C128(1, 2); BARR2; STAGE8(7, 1); STAGEF(0, 2);  // P2: u4,u5
    WAITV(4); BARR1; C128(0, 1); BARR2; STAGEF(1, 0); STAGEF(2, 1);  // P3: u6,u7
    WAITV(8); BARR1; C16(2); BARR2; STAGEF(3, 2);                    // F0
    WAITV(8); BARR1; C16(0); BARR2; STAGEF(4, 0);                    // F1
    WAITV(8); BARR1; C16(1);                                         // F2
    WAITV(4); BARR1; C16(2);                                         // F3
    WAITV(0); BARR1; C16(0);                                         // F4

    // ---- Epilogue: Dc = nci + ncj - acc*(2/4096); K = exp(-max(Dc,0)) ----
    float nci[16], ncj[4];
#pragma unroll
    for (int a = 0; a < 4; ++a)
#pragma unroll
        for (int r = 0; r < 4; ++r)
            nci[a * 4 + r] = normC[ri + i0w + 16 * a + 4 * g + r];
#pragma unroll
    for (int b = 0; b < 4; ++b)
        ncj[b] = normC[rj + j0w + 16 * b + l15];

    float sgn = ((ri < NHALF) == (rj < NHALF)) ? 1.f : -1.f;
    float wsgn = 2.f * sgn;
    const float cf = 2.f / 4096.f;

    float locf = 0.f;
#pragma unroll
    for (int a = 0; a < 4; ++a)
#pragma unroll
        for (int b = 0; b < 4; ++b)
#pragma unroll
            for (int r = 0; r < 4; ++r) {
                int gi = ri + i0w + 16 * a + 4 * g + r;
                int gj = rj + j0w + 16 * b + l15;
                float Dc = fmaxf(fmaf(-cf, acc[a][b][r], nci[a * 4 + r] + ncj[b]), 0.f);
                float K = __expf(-Dc);
                float w = (gj > gi && gj != gi + NHALF) ? wsgn : 0.f;
                locf = fmaf(w, K, locf);
            }
    double loc = (double)locf;
#pragma unroll
    for (int m = 32; m >= 1; m >>= 1) loc += __shfl_xor(loc, m, 64);
    if (lane == 0) sredC[wave] = loc;
    __syncthreads();
    if (tid == 0) {
        double S = sredC[0] + sredC[1] + sredC[2] + sredC[3];
        long long q = (long long)llrint(S * FIXSCALE);
        atomicAdd(accI, (unsigned long long)q);
        __threadfence();
        unsigned done = atomicAdd(doneCnt, 1u);
        if (done == NTRI - 1) {
            __threadfence();
            unsigned long long raw = atomicAdd(accI, 0ULL);  // device-scope coherent read
            double tot = (double)(long long)raw / FIXSCALE;
            out[0] = (float)(tot / (4096.0 * 4095.0));
        }
    }
#undef STAGE8
#undef STAGEF
#undef C128
#undef C16
#undef WAITV
#undef BARR1
#undef BARR2
}

extern "C" void kernel_launch(void* const* d_in, const int* in_sizes, int n_in,
                              void* d_out, int out_size, void* d_ws, size_t ws_size,
                              hipStream_t stream)
{
    const float* Xs  = (const float*)d_in[0];
    const float* Xt  = (const float*)d_in[1];
    const float* W1  = (const float*)d_in[2];
    const float* b1  = (const float*)d_in[3];
    const float* W2  = (const float*)d_in[4];
    const float* b2  = (const float*)d_in[5];
    const float* W3  = (const float*)d_in[6];
    const float* b3  = (const float*)d_in[7];
    const float* W4  = (const float*)d_in[8];
    const float* b4  = (const float*)d_in[9];
    const float* sigP  = (const float*)d_in[11];
    const float* sig0P = (const float*)d_in[12];
    float* out = (float*)d_out;

    char* ws = (char*)d_ws;
    char* Xb8 = ws;                                               // 4 MB
    unsigned short* FpkA = (unsigned short*)(ws + 8 * T64STRIDE); // 8192*160*2 B
    unsigned short* FpkB = FpkA + (size_t)NTOT * FPS;             // 8192*160*2 B
    float* normC = (float*)(FpkB + (size_t)NTOT * FPS);           // 8192 f32
    unsigned long long* accI = (unsigned long long*)(normC + NTOT); // 8 B (8-aligned)
    unsigned int* doneCnt = (unsigned int*)(accI + 1);              // 4 B

    hipMemsetAsync((void*)accI, 0, 16, stream);   // zero accumulator + counter each call

    featurize_kernel<<<dim3(1024), dim3(256), 0, stream>>>(
        Xs, Xt, W1, b1, W2, b2, W3, b3, W4, b4, sigP, sig0P,
        FpkA, FpkB, normC, Xb8);
    pairwise_kernel<<<dim3(NTRI), dim3(256), 0, stream>>>(
        Xb8, FpkA, FpkB, normC, accI, doneCnt, out);
}

// Round 17
// 65.428 us; speedup vs baseline: 1.8308x; 1.8308x over previous
//
#include <hip/hip_runtime.h>
#include <math.h>

#define NHALF 4096
#define NTOT  8192
#define DIN   512
#define DFR   50     // real deep-feature dim
#define FPS   160    // packed feature row length (shorts): [50|50|50|10 pad]
#define BM    128    // tile M = N
#define NBI   64     // 8192/128
#define NTRI  2080   // 64*65/2 upper-tri blocks
// Xb8 layout: [t64 0..7][kc 0..7][row 0..8191][8B]; strides 524288 / 65536 / 8
#define T64STRIDE 524288
#define KCSTRIDE  65536

typedef short short8 __attribute__((ext_vector_type(8)));
typedef float f32x4 __attribute__((ext_vector_type(4)));
typedef int   i32x8 __attribute__((ext_vector_type(8)));

__device__ __forceinline__ float softplus_f(float x) {
    return fmaxf(x, 0.f) + log1pf(expf(-fabsf(x)));
}

__device__ __forceinline__ unsigned cvt_pk_bf16(float lo, float hi) {
    unsigned r;
    asm("v_cvt_pk_bf16_f32 %0, %1, %2" : "=v"(r) : "v"(lo), "v"(hi));
    return r;
}

__device__ __forceinline__ unsigned short bf16_rne(float v) {
    return (unsigned short)(cvt_pk_bf16(v, 0.f) & 0xffffu);
}

__device__ __forceinline__ float bf16_to_f(unsigned short s) {
    union { unsigned u; float f; } c;
    c.u = (unsigned)s << 16;
    return c.f;
}

__device__ __forceinline__ void gload_lds16(const void* g, void* l) {
    __builtin_amdgcn_global_load_lds(
        (const __attribute__((address_space(1))) void*)g,
        (__attribute__((address_space(3))) void*)l, 16, 0, 0);
}

// ---------------- Kernel A: featurize (LANE-PARALLEL, round-15 proven) ----------------
// X: q = e4m3(64*x/sigmaOPT) stored transposed [t64][kc][row]; norms from
// DEQUANTIZED q. F: f = 64*o/sigma0OPT as bf16 hi+lo packs. Layers 2-4:
// lane j owns neuron j (1 softplus each), broadcast via shfl. ep-terms dropped.
__global__ __launch_bounds__(256) void featurize_kernel(
    const float* __restrict__ Xs, const float* __restrict__ Xt,
    const float* __restrict__ W1, const float* __restrict__ b1,
    const float* __restrict__ W2, const float* __restrict__ b2,
    const float* __restrict__ W3, const float* __restrict__ b3,
    const float* __restrict__ W4, const float* __restrict__ b4,
    const float* __restrict__ sigP, const float* __restrict__ sig0P,
    unsigned short* __restrict__ FpkA, unsigned short* __restrict__ FpkB,
    float* __restrict__ normC, char* __restrict__ Xb8)
{
    __shared__ float W1L[80 * 65];                       // 20.8 KB
    __shared__ __align__(16) unsigned short pkA[4][FPS];
    __shared__ __align__(16) unsigned short pkB[4][FPS];
    int tid = threadIdx.x;
    for (int e = tid; e < 5120; e += 256) {
        int r = e / 10, j = e - 10 * r;
        W1L[((r & 7) * 10 + j) * 65 + (r >> 3)] = W1[e];
    }
    __syncthreads();

    int row  = (blockIdx.x * blockDim.x + tid) >> 6;
    int lane = tid & 63, wv = tid >> 6;
    float alpha8 = 64.f / sigP[0];    // 64/sigmaOPT
    float beta   = 64.f / sig0P[0];   // 64/sigma0OPT
    const float* src = (row < NHALF) ? (Xs + (size_t)row * DIN)
                                     : (Xt + (size_t)(row - NHALF) * DIN);
    float4 v0 = ((const float4*)src)[lane * 2];
    float4 v1 = ((const float4*)src)[lane * 2 + 1];
    float x[8] = {v0.x, v0.y, v0.z, v0.w, v1.x, v1.y, v1.z, v1.w};

    // fp8 quantize (x64 scale), dequantized norm
    float z[8];
#pragma unroll
    for (int t = 0; t < 8; ++t) z[t] = x[t] * alpha8;
    unsigned w0 = 0, w1 = 0;
    w0 = __builtin_amdgcn_cvt_pk_fp8_f32(z[0], z[1], w0, false);
    w0 = __builtin_amdgcn_cvt_pk_fp8_f32(z[2], z[3], w0, true);
    w1 = __builtin_amdgcn_cvt_pk_fp8_f32(z[4], z[5], w1, false);
    w1 = __builtin_amdgcn_cvt_pk_fp8_f32(z[6], z[7], w1, true);
    float on = 0.f, qf;
    qf = __builtin_amdgcn_cvt_f32_fp8(w0, 0); on = fmaf(qf, qf, on);
    qf = __builtin_amdgcn_cvt_f32_fp8(w0, 1); on = fmaf(qf, qf, on);
    qf = __builtin_amdgcn_cvt_f32_fp8(w0, 2); on = fmaf(qf, qf, on);
    qf = __builtin_amdgcn_cvt_f32_fp8(w0, 3); on = fmaf(qf, qf, on);
    qf = __builtin_amdgcn_cvt_f32_fp8(w1, 0); on = fmaf(qf, qf, on);
    qf = __builtin_amdgcn_cvt_f32_fp8(w1, 1); on = fmaf(qf, qf, on);
    qf = __builtin_amdgcn_cvt_f32_fp8(w1, 2); on = fmaf(qf, qf, on);
    qf = __builtin_amdgcn_cvt_f32_fp8(w1, 3); on = fmaf(qf, qf, on);
    *(uint2*)(Xb8 + (lane >> 3) * T64STRIDE + (lane & 7) * KCSTRIDE
              + (size_t)row * 8) = make_uint2(w0, w1);

    float p[10];
#pragma unroll
    for (int j = 0; j < 10; ++j) p[j] = 0.f;
#pragma unroll
    for (int t = 0; t < 8; ++t) {
        float xv = x[t];
#pragma unroll
        for (int j = 0; j < 10; ++j)
            p[j] = fmaf(xv, W1L[(t * 10 + j) * 65 + lane], p[j]);
    }
#pragma unroll
    for (int m = 32; m >= 1; m >>= 1) {
#pragma unroll
        for (int j = 0; j < 10; ++j) p[j] += __shfl_xor(p[j], m, 64);
        on += __shfl_xor(on, m, 64);
    }
    // layers 2-4: lane-parallel neurons (lane j owns neuron j%10)
    int lane10 = lane % 10;
    float pown = p[0];
#pragma unroll
    for (int j = 1; j < 10; ++j) pown = (lane10 == j) ? p[j] : pown;
    float hown = softplus_f(pown + b1[lane10]);
    float h1b[10];
#pragma unroll
    for (int k = 0; k < 10; ++k) h1b[k] = __shfl(hown, k, 64);

    float a2 = b2[lane10];
#pragma unroll
    for (int k = 0; k < 10; ++k) a2 = fmaf(h1b[k], W2[k * 10 + lane10], a2);
    float h2own = softplus_f(a2);
    float h2b[10];
#pragma unroll
    for (int k = 0; k < 10; ++k) h2b[k] = __shfl(h2own, k, 64);

    float a3 = b3[lane10];
#pragma unroll
    for (int k = 0; k < 10; ++k) a3 = fmaf(h2b[k], W3[k * 10 + lane10], a3);
    float h3own = softplus_f(a3);
    float h3b[10];
#pragma unroll
    for (int k = 0; k < 10; ++k) h3b[k] = __shfl(h3own, k, 64);

    float o = 0.f;
    if (lane < DFR) {
        float a = b4[lane];
#pragma unroll
        for (int k = 0; k < 10; ++k) a = fmaf(h3b[k], W4[k * 50 + lane], a);
        o = a;
    }
    // scaled split-pack: f = beta*o = hi + lo (both bf16)
    float f = o * beta;
    unsigned short hi_s = bf16_rne(f);
    unsigned short lo_s = bf16_rne(f - bf16_to_f(hi_s));
    if (lane < DFR) {
        pkA[wv][lane] = hi_s;  pkA[wv][50 + lane] = hi_s;  pkA[wv][100 + lane] = lo_s;
        pkB[wv][lane] = hi_s;  pkB[wv][50 + lane] = lo_s;  pkB[wv][100 + lane] = hi_s;
    } else if (lane < 60) {
        pkA[wv][100 + lane] = 0;   // pad 150..159
        pkB[wv][100 + lane] = 0;
    }
    __syncthreads();
    if (lane < 20)
        *(uint4*)(FpkA + (size_t)row * FPS + lane * 8) = *(const uint4*)&pkA[wv][lane * 8];
    else if (lane < 40)
        *(uint4*)(FpkB + (size_t)row * FPS + (lane - 20) * 8) = *(const uint4*)&pkB[wv][(lane - 20) * 8];

    float fn = f * f;
#pragma unroll
    for (int m = 32; m >= 1; m >>= 1) fn += __shfl_xor(fn, m, 64);
    if (lane == 0) normC[row] = (on + fn) * (1.f / 4096.f);
}

// ---------------- Kernel C: MX-scaled fp8(X) + bf16(F) MFMA pairwise, upper-tri ----------------
// (round-15 proven) 4 x K=128 mfma_scale_f32_16x16x128_f8f6f4 (scale = 1.0 exact)
// + 5 x K=32 bf16; 3 x 16KB slots, counted vmcnt; BARR1/BARR2 race-free barriers.
__global__ __launch_bounds__(256, 3) void pairwise_kernel(
    const char* __restrict__ Xb8,
    const unsigned short* __restrict__ FpkA,
    const unsigned short* __restrict__ FpkB,
    const float* __restrict__ normC,
    double* __restrict__ partialsC)
{
    __shared__ char smem[49152] __attribute__((aligned(128)));
    __shared__ double sredC[4];

    int bid = blockIdx.x;
    int bi = (int)((129.0 - sqrt(16641.0 - 8.0 * (double)bid)) * 0.5);
    while (NBI * (bi + 1) - (bi + 1) * bi / 2 <= bid) ++bi;
    while (NBI * bi - bi * (bi - 1) / 2 > bid) --bi;
    int bj = bi + (bid - (NBI * bi - bi * (bi - 1) / 2));

    int tid = threadIdx.x;
    int lane = tid & 63, wave = tid >> 6;
    int g = lane >> 4, l15 = lane & 15;
    int i0w = (wave >> 1) * 64;
    int j0w = (wave & 1) * 64;
    int ri = bi * BM, rj = bj * BM;

    const char* sA8 = Xb8 + wave * KCSTRIDE + (size_t)(ri + 2 * lane) * 8;
    const char* sB8 = Xb8 + wave * KCSTRIDE + (size_t)(rj + 2 * lane) * 8;
    int srow = tid >> 2;
    int schunk = (tid & 3) ^ ((srow >> 1) & 3);
    const char* fA0 = (const char*)(FpkA + (size_t)(ri + srow) * FPS) + schunk * 16;
    const char* fB0 = (const char*)(FpkB + (size_t)(rj + srow) * FPS) + schunk * 16;
    char* lwave = (char*)smem + wave * 1024;

    // F fragment read offsets (swizzled, shorts): row pitch 32, chunk 8
    int swz = (l15 >> 1) & 3;
    int offA = (i0w + l15) * 32 + (g ^ swz) * 8;
    int offB = (j0w + l15) * 32 + (g ^ swz) * 8;

    f32x4 acc[4][4];
#pragma unroll
    for (int a = 0; a < 4; ++a)
#pragma unroll
        for (int b = 0; b < 4; ++b) acc[a][b] = (f32x4){0.f, 0.f, 0.f, 0.f};

#define STAGE8(kt, buf)                                              \
    do {                                                             \
        char* ld_ = lwave + (buf) * 16384;                           \
        const char* a_ = sA8 + (kt) * T64STRIDE;                     \
        const char* b_ = sB8 + (kt) * T64STRIDE;                     \
        gload_lds16(a_,                ld_);                         \
        gload_lds16(a_ + 4 * KCSTRIDE, ld_ + 4096);                  \
        gload_lds16(b_,                ld_ + 8192);                  \
        gload_lds16(b_ + 4 * KCSTRIDE, ld_ + 12288);                 \
    } while (0)

#define STAGEF(kf, buf)                                              \
    do {                                                             \
        char* ld_ = lwave + (buf) * 16384;                           \
        const char* gA_ = fA0 + (kf) * 64;                           \
        const char* gB_ = fB0 + (kf) * 64;                           \
        gload_lds16(gA_,         ld_);                               \
        gload_lds16(gA_ + 20480, ld_ + 4096);                        \
        gload_lds16(gB_,         ld_ + 8192);                        \
        gload_lds16(gB_ + 20480, ld_ + 12288);                       \
    } while (0)

// K=128 MX-scaled phase consuming slot pair (pa = t64 even, pb = t64 odd).
#define C128(pa, pb)                                                               \
    do {                                                                           \
        const char* slA_ = smem + (((lane & 32) ? (pb) : (pa)) * 16384);           \
        int kcb_ = ((lane >> 4) & 1) << 2;                                         \
        const char* baseA_ = slA_ + kcb_ * 1024 + (i0w + l15) * 8;                 \
        const char* baseB_ = slA_ + 8192 + kcb_ * 1024 + (j0w + l15) * 8;          \
        i32x8 af_[4];                                                              \
        _Pragma("unroll")                                                          \
        for (int a = 0; a < 4; ++a) {                                              \
            const char* p_ = baseA_ + a * 128;                                     \
            uint2 t0 = *(const uint2*)(p_);                                        \
            uint2 t1 = *(const uint2*)(p_ + 1024);                                 \
            uint2 t2 = *(const uint2*)(p_ + 2048);                                 \
            uint2 t3 = *(const uint2*)(p_ + 3072);                                 \
            af_[a] = (i32x8){(int)t0.x, (int)t0.y, (int)t1.x, (int)t1.y,           \
                             (int)t2.x, (int)t2.y, (int)t3.x, (int)t3.y};          \
        }                                                                          \
        __builtin_amdgcn_s_setprio(1);                                             \
        _Pragma("unroll")                                                          \
        for (int b = 0; b < 4; ++b) {                                              \
            const char* p_ = baseB_ + b * 128;                                     \
            uint2 t0 = *(const uint2*)(p_);                                        \
            uint2 t1 = *(const uint2*)(p_ + 1024);                                 \
            uint2 t2 = *(const uint2*)(p_ + 2048);                                 \
            uint2 t3 = *(const uint2*)(p_ + 3072);                                 \
            i32x8 bf_ = (i32x8){(int)t0.x, (int)t0.y, (int)t1.x, (int)t1.y,        \
                                (int)t2.x, (int)t2.y, (int)t3.x, (int)t3.y};       \
            _Pragma("unroll")                                                      \
            for (int a = 0; a < 4; ++a)                                            \
                acc[a][b] = __builtin_amdgcn_mfma_scale_f32_16x16x128_f8f6f4(      \
                    af_[a], bf_, acc[a][b], 0, 0,                                  \
                    0, 0x7f7f7f7f, 0, 0x7f7f7f7f);                                 \
        }                                                                          \
        __builtin_amdgcn_s_setprio(0);                                             \
    } while (0)

#define C16(buf)                                                                   \
    do {                                                                           \
        const unsigned short* tc_ = (const unsigned short*)(smem + (buf) * 16384); \
        short8 af_[4], bf_[4];                                                     \
        _Pragma("unroll")                                                          \
        for (int a = 0; a < 4; ++a)                                                \
            af_[a] = *(const short8*)(tc_ + offA + a * 512);                       \
        _Pragma("unroll")                                                          \
        for (int b = 0; b < 4; ++b)                                                \
            bf_[b] = *(const short8*)(tc_ + 4096 + offB + b * 512);                \
        __builtin_amdgcn_s_setprio(1);                                             \
        _Pragma("unroll")                                                          \
        for (int a = 0; a < 4; ++a)                                                \
            _Pragma("unroll")                                                      \
            for (int b = 0; b < 4; ++b)                                            \
                acc[a][b] = __builtin_amdgcn_mfma_f32_16x16x32_bf16(               \
                    af_[a], bf_[b], acc[a][b], 0, 0, 0);                           \
        __builtin_amdgcn_s_setprio(0);                                             \
    } while (0)

#define WAITV(N) do { asm volatile("s_waitcnt vmcnt(" #N ")" ::: "memory");        \
                      __builtin_amdgcn_sched_barrier(0); } while (0)
#define BARR1    do { __builtin_amdgcn_s_barrier();                                \
                      __builtin_amdgcn_sched_barrier(0); } while (0)
#define BARR2    do { __builtin_amdgcn_sched_barrier(0);                           \
                      asm volatile("s_waitcnt lgkmcnt(0)" ::: "memory");           \
                      __builtin_amdgcn_sched_barrier(0);                           \
                      __builtin_amdgcn_s_barrier();                                \
                      __builtin_amdgcn_sched_barrier(0); } while (0)

    // ---- 9-phase pipelined loop: units u0..u7 (X t64) + f0..f4 (F) ----
    STAGE8(0, 0); STAGE8(1, 1); STAGE8(2, 2);
    WAITV(4); BARR1; C128(0, 1); BARR2; STAGE8(3, 0); STAGE8(4, 1);  // P0: u0,u1
    WAITV(4); BARR1; C128(2, 0); BARR2; STAGE8(5, 2); STAGE8(6, 0);  // P1: u2,u3
    WAITV(4); BARR1; C128(1, 2); BARR2; STAGE8(7, 1); STAGEF(0, 2);  // P2: u4,u5
    WAITV(4); BARR1; C128(0, 1); BARR2; STAGEF(1, 0); STAGEF(2, 1);  // P3: u6,u7
    WAITV(8); BARR1; C16(2); BARR2; STAGEF(3, 2);                    // F0
    WAITV(8); BARR1; C16(0); BARR2; STAGEF(4, 0);                    // F1
    WAITV(8); BARR1; C16(1);                                         // F2
    WAITV(4); BARR1; C16(2);                                         // F3
    WAITV(0); BARR1; C16(0);                                         // F4

    // ---- Epilogue: Dc = nci + ncj - acc*(2/4096); K = exp(-max(Dc,0)) ----
    float nci[16], ncj[4];
#pragma unroll
    for (int a = 0; a < 4; ++a)
#pragma unroll
        for (int r = 0; r < 4; ++r)
            nci[a * 4 + r] = normC[ri + i0w + 16 * a + 4 * g + r];
#pragma unroll
    for (int b = 0; b < 4; ++b)
        ncj[b] = normC[rj + j0w + 16 * b + l15];

    float sgn = ((ri < NHALF) == (rj < NHALF)) ? 1.f : -1.f;
    float wsgn = 2.f * sgn;
    const float cf = 2.f / 4096.f;

    float locf = 0.f;
#pragma unroll
    for (int a = 0; a < 4; ++a)
#pragma unroll
        for (int b = 0; b < 4; ++b)
#pragma unroll
            for (int r = 0; r < 4; ++r) {
                int gi = ri + i0w + 16 * a + 4 * g + r;
                int gj = rj + j0w + 16 * b + l15;
                float Dc = fmaxf(fmaf(-cf, acc[a][b][r], nci[a * 4 + r] + ncj[b]), 0.f);
                float K = __expf(-Dc);
                float w = (gj > gi && gj != gi + NHALF) ? wsgn : 0.f;
                locf = fmaf(w, K, locf);
            }
    double loc = (double)locf;
#pragma unroll
    for (int m = 32; m >= 1; m >>= 1) loc += __shfl_xor(loc, m, 64);
    if (lane == 0) sredC[wave] = loc;
    __syncthreads();
    if (tid == 0)
        partialsC[bid] = sredC[0] + sredC[1] + sredC[2] + sredC[3];
#undef STAGE8
#undef STAGEF
#undef C128
#undef C16
#undef WAITV
#undef BARR1
#undef BARR2
}

// ---------------- Kernel D: final reduce ----------------
__global__ __launch_bounds__(256) void reduce_kernel(
    const double* __restrict__ partialsC, float* __restrict__ out)
{
    double s = 0.0;
    for (int i = threadIdx.x; i < NTRI; i += 256) s += partialsC[i];
#pragma unroll
    for (int m = 32; m >= 1; m >>= 1) s += __shfl_xor(s, m, 64);
    __shared__ double ss[4];
    int w = threadIdx.x >> 6;
    if ((threadIdx.x & 63) == 0) ss[w] = s;
    __syncthreads();
    if (threadIdx.x == 0) {
        double S = ss[0] + ss[1] + ss[2] + ss[3];
        out[0] = (float)(S / (4096.0 * 4095.0));
    }
}

extern "C" void kernel_launch(void* const* d_in, const int* in_sizes, int n_in,
                              void* d_out, int out_size, void* d_ws, size_t ws_size,
                              hipStream_t stream)
{
    const float* Xs  = (const float*)d_in[0];
    const float* Xt  = (const float*)d_in[1];
    const float* W1  = (const float*)d_in[2];
    const float* b1  = (const float*)d_in[3];
    const float* W2  = (const float*)d_in[4];
    const float* b2  = (const float*)d_in[5];
    const float* W3  = (const float*)d_in[6];
    const float* b3  = (const float*)d_in[7];
    const float* W4  = (const float*)d_in[8];
    const float* b4  = (const float*)d_in[9];
    const float* sigP  = (const float*)d_in[11];
    const float* sig0P = (const float*)d_in[12];
    float* out = (float*)d_out;

    char* ws = (char*)d_ws;
    char* Xb8 = ws;                                               // 4 MB
    unsigned short* FpkA = (unsigned short*)(ws + 8 * T64STRIDE); // 8192*160*2 B
    unsigned short* FpkB = FpkA + (size_t)NTOT * FPS;             // 8192*160*2 B
    float* normC = (float*)(FpkB + (size_t)NTOT * FPS);           // 8192
    double* partialsC = (double*)(normC + NTOT);                  // 2080

    featurize_kernel<<<dim3(2048), dim3(256), 0, stream>>>(
        Xs, Xt, W1, b1, W2, b2, W3, b3, W4, b4, sigP, sig0P,
        FpkA, FpkB, normC, Xb8);
    pairwise_kernel<<<dim3(NTRI), dim3(256), 0, stream>>>(
        Xb8, FpkA, FpkB, normC, partialsC);
    reduce_kernel<<<dim3(1), dim3(256), 0, stream>>>(partialsC, out);
}

// Round 18
// 63.926 us; speedup vs baseline: 1.8738x; 1.0235x over previous
//
#include <hip/hip_runtime.h>
#include <math.h>

#define NHALF 4096
#define NTOT  8192
#define DIN   512
#define DFR   50     // real deep-feature dim
#define FPS   160    // packed feature row length (shorts): [50|50|50|10 pad]
#define BM    128    // tile M = N
#define NBI   64     // 8192/128
#define NTRI  2080   // 64*65/2 upper-tri blocks
// Xb8 layout: [t64 0..7][kc 0..7][row 0..8191][8B]; strides 524288 / 65536 / 8
#define T64STRIDE 524288
#define KCSTRIDE  65536

typedef short short8 __attribute__((ext_vector_type(8)));
typedef float f32x4 __attribute__((ext_vector_type(4)));
typedef int   i32x8 __attribute__((ext_vector_type(8)));

__device__ __forceinline__ float softplus_f(float x) {
    return fmaxf(x, 0.f) + log1pf(expf(-fabsf(x)));
}

__device__ __forceinline__ unsigned cvt_pk_bf16(float lo, float hi) {
    unsigned r;
    asm("v_cvt_pk_bf16_f32 %0, %1, %2" : "=v"(r) : "v"(lo), "v"(hi));
    return r;
}

__device__ __forceinline__ unsigned short bf16_rne(float v) {
    return (unsigned short)(cvt_pk_bf16(v, 0.f) & 0xffffu);
}

__device__ __forceinline__ float bf16_to_f(unsigned short s) {
    union { unsigned u; float f; } c;
    c.u = (unsigned)s << 16;
    return c.f;
}

__device__ __forceinline__ void gload_lds16(const void* g, void* l) {
    __builtin_amdgcn_global_load_lds(
        (const __attribute__((address_space(1))) void*)g,
        (__attribute__((address_space(3))) void*)l, 16, 0, 0);
}

// ---------------- Kernel A: featurize (LANE-PARALLEL, round-15 proven) ----------------
// X: q = e4m3(64*x/sigmaOPT) stored transposed [t64][kc][row]; norms from
// DEQUANTIZED q. F: f = 64*o/sigma0OPT as bf16 hi+lo packs. Layers 2-4:
// lane j owns neuron j (1 softplus each), broadcast via shfl. ep-terms dropped.
__global__ __launch_bounds__(256) void featurize_kernel(
    const float* __restrict__ Xs, const float* __restrict__ Xt,
    const float* __restrict__ W1, const float* __restrict__ b1,
    const float* __restrict__ W2, const float* __restrict__ b2,
    const float* __restrict__ W3, const float* __restrict__ b3,
    const float* __restrict__ W4, const float* __restrict__ b4,
    const float* __restrict__ sigP, const float* __restrict__ sig0P,
    unsigned short* __restrict__ FpkA, unsigned short* __restrict__ FpkB,
    float* __restrict__ normC, char* __restrict__ Xb8)
{
    __shared__ float W1L[80 * 65];                       // 20.8 KB
    __shared__ __align__(16) unsigned short pkA[4][FPS];
    __shared__ __align__(16) unsigned short pkB[4][FPS];
    int tid = threadIdx.x;
    for (int e = tid; e < 5120; e += 256) {
        int r = e / 10, j = e - 10 * r;
        W1L[((r & 7) * 10 + j) * 65 + (r >> 3)] = W1[e];
    }
    __syncthreads();

    int row  = (blockIdx.x * blockDim.x + tid) >> 6;
    int lane = tid & 63, wv = tid >> 6;
    float alpha8 = 64.f / sigP[0];    // 64/sigmaOPT
    float beta   = 64.f / sig0P[0];   // 64/sigma0OPT
    const float* src = (row < NHALF) ? (Xs + (size_t)row * DIN)
                                     : (Xt + (size_t)(row - NHALF) * DIN);
    float4 v0 = ((const float4*)src)[lane * 2];
    float4 v1 = ((const float4*)src)[lane * 2 + 1];
    float x[8] = {v0.x, v0.y, v0.z, v0.w, v1.x, v1.y, v1.z, v1.w};

    // fp8 quantize (x64 scale), dequantized norm
    float z[8];
#pragma unroll
    for (int t = 0; t < 8; ++t) z[t] = x[t] * alpha8;
    unsigned w0 = 0, w1 = 0;
    w0 = __builtin_amdgcn_cvt_pk_fp8_f32(z[0], z[1], w0, false);
    w0 = __builtin_amdgcn_cvt_pk_fp8_f32(z[2], z[3], w0, true);
    w1 = __builtin_amdgcn_cvt_pk_fp8_f32(z[4], z[5], w1, false);
    w1 = __builtin_amdgcn_cvt_pk_fp8_f32(z[6], z[7], w1, true);
    float on = 0.f, qf;
    qf = __builtin_amdgcn_cvt_f32_fp8(w0, 0); on = fmaf(qf, qf, on);
    qf = __builtin_amdgcn_cvt_f32_fp8(w0, 1); on = fmaf(qf, qf, on);
    qf = __builtin_amdgcn_cvt_f32_fp8(w0, 2); on = fmaf(qf, qf, on);
    qf = __builtin_amdgcn_cvt_f32_fp8(w0, 3); on = fmaf(qf, qf, on);
    qf = __builtin_amdgcn_cvt_f32_fp8(w1, 0); on = fmaf(qf, qf, on);
    qf = __builtin_amdgcn_cvt_f32_fp8(w1, 1); on = fmaf(qf, qf, on);
    qf = __builtin_amdgcn_cvt_f32_fp8(w1, 2); on = fmaf(qf, qf, on);
    qf = __builtin_amdgcn_cvt_f32_fp8(w1, 3); on = fmaf(qf, qf, on);
    *(uint2*)(Xb8 + (lane >> 3) * T64STRIDE + (lane & 7) * KCSTRIDE
              + (size_t)row * 8) = make_uint2(w0, w1);

    float p[10];
#pragma unroll
    for (int j = 0; j < 10; ++j) p[j] = 0.f;
#pragma unroll
    for (int t = 0; t < 8; ++t) {
        float xv = x[t];
#pragma unroll
        for (int j = 0; j < 10; ++j)
            p[j] = fmaf(xv, W1L[(t * 10 + j) * 65 + lane], p[j]);
    }
#pragma unroll
    for (int m = 32; m >= 1; m >>= 1) {
#pragma unroll
        for (int j = 0; j < 10; ++j) p[j] += __shfl_xor(p[j], m, 64);
        on += __shfl_xor(on, m, 64);
    }
    // layers 2-4: lane-parallel neurons (lane j owns neuron j%10)
    int lane10 = lane % 10;
    float pown = p[0];
#pragma unroll
    for (int j = 1; j < 10; ++j) pown = (lane10 == j) ? p[j] : pown;
    float hown = softplus_f(pown + b1[lane10]);
    float h1b[10];
#pragma unroll
    for (int k = 0; k < 10; ++k) h1b[k] = __shfl(hown, k, 64);

    float a2 = b2[lane10];
#pragma unroll
    for (int k = 0; k < 10; ++k) a2 = fmaf(h1b[k], W2[k * 10 + lane10], a2);
    float h2own = softplus_f(a2);
    float h2b[10];
#pragma unroll
    for (int k = 0; k < 10; ++k) h2b[k] = __shfl(h2own, k, 64);

    float a3 = b3[lane10];
#pragma unroll
    for (int k = 0; k < 10; ++k) a3 = fmaf(h2b[k], W3[k * 10 + lane10], a3);
    float h3own = softplus_f(a3);
    float h3b[10];
#pragma unroll
    for (int k = 0; k < 10; ++k) h3b[k] = __shfl(h3own, k, 64);

    float o = 0.f;
    if (lane < DFR) {
        float a = b4[lane];
#pragma unroll
        for (int k = 0; k < 10; ++k) a = fmaf(h3b[k], W4[k * 50 + lane], a);
        o = a;
    }
    // scaled split-pack: f = beta*o = hi + lo (both bf16)
    float f = o * beta;
    unsigned short hi_s = bf16_rne(f);
    unsigned short lo_s = bf16_rne(f - bf16_to_f(hi_s));
    if (lane < DFR) {
        pkA[wv][lane] = hi_s;  pkA[wv][50 + lane] = hi_s;  pkA[wv][100 + lane] = lo_s;
        pkB[wv][lane] = hi_s;  pkB[wv][50 + lane] = lo_s;  pkB[wv][100 + lane] = hi_s;
    } else if (lane < 60) {
        pkA[wv][100 + lane] = 0;   // pad 150..159
        pkB[wv][100 + lane] = 0;
    }
    __syncthreads();
    if (lane < 20)
        *(uint4*)(FpkA + (size_t)row * FPS + lane * 8) = *(const uint4*)&pkA[wv][lane * 8];
    else if (lane < 40)
        *(uint4*)(FpkB + (size_t)row * FPS + (lane - 20) * 8) = *(const uint4*)&pkB[wv][(lane - 20) * 8];

    float fn = f * f;
#pragma unroll
    for (int m = 32; m >= 1; m >>= 1) fn += __shfl_xor(fn, m, 64);
    if (lane == 0) normC[row] = (on + fn) * (1.f / 4096.f);
}

// ---------------- Kernel C: MX-scaled fp8(X) + bf16(F) MFMA pairwise, upper-tri ----------------
// (round-15 proven compute) + T1 XCD-aware bid swizzle (2080 = 8*260, bijective)
// + block-uniform epilogue fast path (w == wsgn for all but diag/cross blocks).
__global__ __launch_bounds__(256, 3) void pairwise_kernel(
    const char* __restrict__ Xb8,
    const unsigned short* __restrict__ FpkA,
    const unsigned short* __restrict__ FpkB,
    const float* __restrict__ normC,
    double* __restrict__ partialsC)
{
    __shared__ char smem[49152] __attribute__((aligned(128)));
    __shared__ double sredC[4];

    // XCD swizzle: dispatcher round-robins blockIdx%8 across XCDs; give each XCD
    // a contiguous tri-range so A-panels are L2-local. 2080 % 8 == 0 -> bijective.
    int bid = (blockIdx.x & 7) * (NTRI / 8) + (blockIdx.x >> 3);
    int bi = (int)((129.0 - sqrt(16641.0 - 8.0 * (double)bid)) * 0.5);
    while (NBI * (bi + 1) - (bi + 1) * bi / 2 <= bid) ++bi;
    while (NBI * bi - bi * (bi - 1) / 2 > bid) --bi;
    int bj = bi + (bid - (NBI * bi - bi * (bi - 1) / 2));

    int tid = threadIdx.x;
    int lane = tid & 63, wave = tid >> 6;
    int g = lane >> 4, l15 = lane & 15;
    int i0w = (wave >> 1) * 64;
    int j0w = (wave & 1) * 64;
    int ri = bi * BM, rj = bj * BM;

    const char* sA8 = Xb8 + wave * KCSTRIDE + (size_t)(ri + 2 * lane) * 8;
    const char* sB8 = Xb8 + wave * KCSTRIDE + (size_t)(rj + 2 * lane) * 8;
    int srow = tid >> 2;
    int schunk = (tid & 3) ^ ((srow >> 1) & 3);
    const char* fA0 = (const char*)(FpkA + (size_t)(ri + srow) * FPS) + schunk * 16;
    const char* fB0 = (const char*)(FpkB + (size_t)(rj + srow) * FPS) + schunk * 16;
    char* lwave = (char*)smem + wave * 1024;

    // F fragment read offsets (swizzled, shorts): row pitch 32, chunk 8
    int swz = (l15 >> 1) & 3;
    int offA = (i0w + l15) * 32 + (g ^ swz) * 8;
    int offB = (j0w + l15) * 32 + (g ^ swz) * 8;

    f32x4 acc[4][4];
#pragma unroll
    for (int a = 0; a < 4; ++a)
#pragma unroll
        for (int b = 0; b < 4; ++b) acc[a][b] = (f32x4){0.f, 0.f, 0.f, 0.f};

#define STAGE8(kt, buf)                                              \
    do {                                                             \
        char* ld_ = lwave + (buf) * 16384;                           \
        const char* a_ = sA8 + (kt) * T64STRIDE;                     \
        const char* b_ = sB8 + (kt) * T64STRIDE;                     \
        gload_lds16(a_,                ld_);                         \
        gload_lds16(a_ + 4 * KCSTRIDE, ld_ + 4096);                  \
        gload_lds16(b_,                ld_ + 8192);                  \
        gload_lds16(b_ + 4 * KCSTRIDE, ld_ + 12288);                 \
    } while (0)

#define STAGEF(kf, buf)                                              \
    do {                                                             \
        char* ld_ = lwave + (buf) * 16384;                           \
        const char* gA_ = fA0 + (kf) * 64;                           \
        const char* gB_ = fB0 + (kf) * 64;                           \
        gload_lds16(gA_,         ld_);                               \
        gload_lds16(gA_ + 20480, ld_ + 4096);                        \
        gload_lds16(gB_,         ld_ + 8192);                        \
        gload_lds16(gB_ + 20480, ld_ + 12288);                       \
    } while (0)

// K=128 MX-scaled phase consuming slot pair (pa = t64 even, pb = t64 odd).
#define C128(pa, pb)                                                               \
    do {                                                                           \
        const char* slA_ = smem + (((lane & 32) ? (pb) : (pa)) * 16384);           \
        int kcb_ = ((lane >> 4) & 1) << 2;                                         \
        const char* baseA_ = slA_ + kcb_ * 1024 + (i0w + l15) * 8;                 \
        const char* baseB_ = slA_ + 8192 + kcb_ * 1024 + (j0w + l15) * 8;          \
        i32x8 af_[4];                                                              \
        _Pragma("unroll")                                                          \
        for (int a = 0; a < 4; ++a) {                                              \
            const char* p_ = baseA_ + a * 128;                                     \
            uint2 t0 = *(const uint2*)(p_);                                        \
            uint2 t1 = *(const uint2*)(p_ + 1024);                                 \
            uint2 t2 = *(const uint2*)(p_ + 2048);                                 \
            uint2 t3 = *(const uint2*)(p_ + 3072);                                 \
            af_[a] = (i32x8){(int)t0.x, (int)t0.y, (int)t1.x, (int)t1.y,           \
                             (int)t2.x, (int)t2.y, (int)t3.x, (int)t3.y};          \
        }                                                                          \
        __builtin_amdgcn_s_setprio(1);                                             \
        _Pragma("unroll")                                                          \
        for (int b = 0; b < 4; ++b) {                                              \
            const char* p_ = baseB_ + b * 128;                                     \
            uint2 t0 = *(const uint2*)(p_);                                        \
            uint2 t1 = *(const uint2*)(p_ + 1024);                                 \
            uint2 t2 = *(const uint2*)(p_ + 2048);                                 \
            uint2 t3 = *(const uint2*)(p_ + 3072);                                 \
            i32x8 bf_ = (i32x8){(int)t0.x, (int)t0.y, (int)t1.x, (int)t1.y,        \
                                (int)t2.x, (int)t2.y, (int)t3.x, (int)t3.y};       \
            _Pragma("unroll")                                                      \
            for (int a = 0; a < 4; ++a)                                            \
                acc[a][b] = __builtin_amdgcn_mfma_scale_f32_16x16x128_f8f6f4(      \
                    af_[a], bf_, acc[a][b], 0, 0,                                  \
                    0, 0x7f7f7f7f, 0, 0x7f7f7f7f);                                 \
        }                                                                          \
        __builtin_amdgcn_s_setprio(0);                                             \
    } while (0)

#define C16(buf)                                                                   \
    do {                                                                           \
        const unsigned short* tc_ = (const unsigned short*)(smem + (buf) * 16384); \
        short8 af_[4], bf_[4];                                                     \
        _Pragma("unroll")                                                          \
        for (int a = 0; a < 4; ++a)                                                \
            af_[a] = *(const short8*)(tc_ + offA + a * 512);                       \
        _Pragma("unroll")                                                          \
        for (int b = 0; b < 4; ++b)                                                \
            bf_[b] = *(const short8*)(tc_ + 4096 + offB + b * 512);                \
        __builtin_amdgcn_s_setprio(1);                                             \
        _Pragma("unroll")                                                          \
        for (int a = 0; a < 4; ++a)                                                \
            _Pragma("unroll")                                                      \
            for (int b = 0; b < 4; ++b)                                            \
                acc[a][b] = __builtin_amdgcn_mfma_f32_16x16x32_bf16(               \
                    af_[a], bf_[b], acc[a][b], 0, 0, 0);                           \
        __builtin_amdgcn_s_setprio(0);                                             \
    } while (0)

#define WAITV(N) do { asm volatile("s_waitcnt vmcnt(" #N ")" ::: "memory");        \
                      __builtin_amdgcn_sched_barrier(0); } while (0)
#define BARR1    do { __builtin_amdgcn_s_barrier();                                \
                      __builtin_amdgcn_sched_barrier(0); } while (0)
#define BARR2    do { __builtin_amdgcn_sched_barrier(0);                           \
                      asm volatile("s_waitcnt lgkmcnt(0)" ::: "memory");           \
                      __builtin_amdgcn_sched_barrier(0);                           \
                      __builtin_amdgcn_s_barrier();                                \
                      __builtin_amdgcn_sched_barrier(0); } while (0)

    // ---- 9-phase pipelined loop: units u0..u7 (X t64) + f0..f4 (F) ----
    STAGE8(0, 0); STAGE8(1, 1); STAGE8(2, 2);
    WAITV(4); BARR1; C128(0, 1); BARR2; STAGE8(3, 0); STAGE8(4, 1);  // P0: u0,u1
    WAITV(4); BARR1; C128(2, 0); BARR2; STAGE8(5, 2); STAGE8(6, 0);  // P1: u2,u3
    WAITV(4); BARR1; C128(1, 2); BARR2; STAGE8(7, 1); STAGEF(0, 2);  // P2: u4,u5
    WAITV(4); BARR1; C128(0, 1); BARR2; STAGEF(1, 0); STAGEF(2, 1);  // P3: u6,u7
    WAITV(8); BARR1; C16(2); BARR2; STAGEF(3, 2);                    // F0
    WAITV(8); BARR1; C16(0); BARR2; STAGEF(4, 0);                    // F1
    WAITV(8); BARR1; C16(1);                                         // F2
    WAITV(4); BARR1; C16(2);                                         // F3
    WAITV(0); BARR1; C16(0);                                         // F4

    // ---- Epilogue: Dc = nci + ncj - acc*(2/4096); K = exp(-max(Dc,0)) ----
    float nci[16], ncj[4];
#pragma unroll
    for (int a = 0; a < 4; ++a)
#pragma unroll
        for (int r = 0; r < 4; ++r)
            nci[a * 4 + r] = normC[ri + i0w + 16 * a + 4 * g + r];
#pragma unroll
    for (int b = 0; b < 4; ++b)
        ncj[b] = normC[rj + j0w + 16 * b + l15];

    float sgn = ((ri < NHALF) == (rj < NHALF)) ? 1.f : -1.f;
    float wsgn = 2.f * sgn;
    const float cf = 2.f / 4096.f;

    double loc;
    if (bj > bi && bj != bi + NHALF / BM) {
        // fast path (1984/2080 blocks): w == wsgn for every element
        float locf = 0.f;
#pragma unroll
        for (int a = 0; a < 4; ++a)
#pragma unroll
            for (int b = 0; b < 4; ++b)
#pragma unroll
                for (int r = 0; r < 4; ++r) {
                    float Dc = fmaxf(fmaf(-cf, acc[a][b][r], nci[a * 4 + r] + ncj[b]), 0.f);
                    locf += __expf(-Dc);
                }
        loc = (double)(wsgn * locf);
    } else {
        // diag (bi==bj) and cross-diag (bj==bi+32) blocks: per-element weight
        float locf = 0.f;
#pragma unroll
        for (int a = 0; a < 4; ++a)
#pragma unroll
            for (int b = 0; b < 4; ++b)
#pragma unroll
                for (int r = 0; r < 4; ++r) {
                    int gi = ri + i0w + 16 * a + 4 * g + r;
                    int gj = rj + j0w + 16 * b + l15;
                    float Dc = fmaxf(fmaf(-cf, acc[a][b][r], nci[a * 4 + r] + ncj[b]), 0.f);
                    float K = __expf(-Dc);
                    float w = (gj > gi && gj != gi + NHALF) ? wsgn : 0.f;
                    locf = fmaf(w, K, locf);
                }
        loc = (double)locf;
    }
#pragma unroll
    for (int m = 32; m >= 1; m >>= 1) loc += __shfl_xor(loc, m, 64);
    if (lane == 0) sredC[wave] = loc;
    __syncthreads();
    if (tid == 0)
        partialsC[bid] = sredC[0] + sredC[1] + sredC[2] + sredC[3];
#undef STAGE8
#undef STAGEF
#undef C128
#undef C16
#undef WAITV
#undef BARR1
#undef BARR2
}

// ---------------- Kernel D: final reduce ----------------
__global__ __launch_bounds__(256) void reduce_kernel(
    const double* __restrict__ partialsC, float* __restrict__ out)
{
    double s = 0.0;
    for (int i = threadIdx.x; i < NTRI; i += 256) s += partialsC[i];
#pragma unroll
    for (int m = 32; m >= 1; m >>= 1) s += __shfl_xor(s, m, 64);
    __shared__ double ss[4];
    int w = threadIdx.x >> 6;
    if ((threadIdx.x & 63) == 0) ss[w] = s;
    __syncthreads();
    if (threadIdx.x == 0) {
        double S = ss[0] + ss[1] + ss[2] + ss[3];
        out[0] = (float)(S / (4096.0 * 4095.0));
    }
}

extern "C" void kernel_launch(void* const* d_in, const int* in_sizes, int n_in,
                              void* d_out, int out_size, void* d_ws, size_t ws_size,
                              hipStream_t stream)
{
    const float* Xs  = (const float*)d_in[0];
    const float* Xt  = (const float*)d_in[1];
    const float* W1  = (const float*)d_in[2];
    const float* b1  = (const float*)d_in[3];
    const float* W2  = (const float*)d_in[4];
    const float* b2  = (const float*)d_in[5];
    const float* W3  = (const float*)d_in[6];
    const float* b3  = (const float*)d_in[7];
    const float* W4  = (const float*)d_in[8];
    const float* b4  = (const float*)d_in[9];
    const float* sigP  = (const float*)d_in[11];
    const float* sig0P = (const float*)d_in[12];
    float* out = (float*)d_out;

    char* ws = (char*)d_ws;
    char* Xb8 = ws;                                               // 4 MB
    unsigned short* FpkA = (unsigned short*)(ws + 8 * T64STRIDE); // 8192*160*2 B
    unsigned short* FpkB = FpkA + (size_t)NTOT * FPS;             // 8192*160*2 B
    float* normC = (float*)(FpkB + (size_t)NTOT * FPS);           // 8192
    double* partialsC = (double*)(normC + NTOT);                  // 2080

    featurize_kernel<<<dim3(2048), dim3(256), 0, stream>>>(
        Xs, Xt, W1, b1, W2, b2, W3, b3, W4, b4, sigP, sig0P,
        FpkA, FpkB, normC, Xb8);
    pairwise_kernel<<<dim3(NTRI), dim3(256), 0, stream>>>(
        Xb8, FpkA, FpkB, normC, partialsC);
    reduce_kernel<<<dim3(1), dim3(256), 0, stream>>>(partialsC, out);
}